// Round 22
// baseline (71.384 us; speedup 1.0000x reference)
//
#include <hip/hip_runtime.h>
#include <cstddef>

#define HW 4096
#define WPITCH 264   // shorts per Wp row (528 B)

typedef __attribute__((ext_vector_type(8))) short short8v;   // 8 bf16
typedef __attribute__((ext_vector_type(4))) float f32x4;     // 4 fp32

__device__ inline unsigned short f2bf(float f) {
    unsigned int u = __float_as_uint(f);
    u += 0x7FFFu + ((u >> 16) & 1u);
    return (unsigned short)(u >> 16);
}
__device__ inline float bf2f(unsigned short s) {
    return __uint_as_float(((unsigned int)s) << 16);
}

// ---------------------------------------------------------------------------
// Reg-staged tile movement for a [128 rows][64 bf16] tile (16 KB), 512-thread
// blocks: per thread 2 x 16B. Layout: slot s of row r at r*128 + ((s^(r&7))<<4).
// ---------------------------------------------------------------------------
__device__ inline void load_tile2(const unsigned short* __restrict__ g, int kc,
                                  int wid, int lane, short8v r[2])
{
    const int s  = lane & 7;
    const int r8 = lane >> 3;
    const unsigned short* src = g + kc + s * 8;
#pragma unroll
    for (int i = 0; i < 2; ++i) {
        const int row = wid * 16 + i * 8 + r8;
        r[i] = *(const short8v*)(src + row * 256);
    }
}

__device__ inline void store_tile2(unsigned short* lds, int wid, int lane, const short8v r[2])
{
    const int s  = lane & 7;
    const int r8 = lane >> 3;
#pragma unroll
    for (int i = 0; i < 2; ++i) {
        const int row = wid * 16 + i * 8 + r8;
        *(short8v*)((char*)lds + row * 128 + ((s ^ (row & 7)) << 4)) = r[i];
    }
}

__device__ inline short8v read_frag(const unsigned short* lds, int row, int kbyte, int lane)
{
    const char* p = (const char*)lds + row * 128 + (kbyte ^ ((lane & 7) * 16));
    return *(const short8v*)p;
}

// ---------------------------------------------------------------------------
// Prep: bf16 weights (row-major), lo-plane for aux weight rows, fp32 biases.
// ---------------------------------------------------------------------------
__global__ __launch_bounds__(256)
void prep_kernel(const float* __restrict__ w_off, const float* __restrict__ b_off,
                 const float* __restrict__ w_attn, const float* __restrict__ b_attn,
                 const float* __restrict__ w_val, const float* __restrict__ b_val,
                 const float* __restrict__ w_out,
                 unsigned short* __restrict__ wcat_bf, unsigned short* __restrict__ wauxlo,
                 unsigned short* __restrict__ wout_bf, float* __restrict__ bcat)
{
    int i = blockIdx.x * 256 + threadIdx.x;
    if (i < 384 * 256) {
        int n = i >> 8, k = i & 255;
        float v;
        if (n < 256)      v = w_val[n * 256 + k];
        else if (n < 320) v = w_off[(n - 256) * 256 + k];
        else if (n < 352) v = w_attn[(n - 320) * 256 + k];
        else              v = 0.0f;
        unsigned short hi = f2bf(v);
        wcat_bf[i] = hi;
        if (n >= 256) wauxlo[(n - 256) * 256 + k] = f2bf(v - bf2f(hi));
    }
    if (i < 128 * 256) {
        int n = i >> 8;
        if (n >= 96) wauxlo[i] = 0;
    }
    if (i < 256 * 256) wout_bf[i] = f2bf(w_out[i]);
    if (i < 512) {
        float v = 0.0f;
        if (i < 256)      v = b_val[i];
        else if (i < 320) v = b_off[i - 256];
        else if (i < 352) v = b_attn[i - 320];
        bcat[i] = v;
    }
}

// ---------------------------------------------------------------------------
// Transpose x: fp32 [b][c][4096] -> bf16 [b][p][256]
// ---------------------------------------------------------------------------
__global__ __launch_bounds__(256)
void transpose_kernel(const float* __restrict__ x, unsigned short* __restrict__ xhi)
{
    __shared__ float t[64][65];
    const int bid = blockIdx.x;
    const int pt = bid & 63, ct = (bid >> 6) & 3, b = bid >> 8;
    const int tid = threadIdx.x;
    const int rr = tid >> 4, c4 = (tid & 15) * 4;

    const float* src = x + ((size_t)(b * 256 + ct * 64)) * HW + pt * 64;
#pragma unroll
    for (int j = 0; j < 4; ++j) {
        float4 v = *(const float4*)&src[(size_t)(j * 16 + rr) * HW + c4];
        t[j * 16 + rr][c4 + 0] = v.x; t[j * 16 + rr][c4 + 1] = v.y;
        t[j * 16 + rr][c4 + 2] = v.z; t[j * 16 + rr][c4 + 3] = v.w;
    }
    __syncthreads();

    const size_t obase = ((size_t)b * HW + pt * 64) * 256 + ct * 64;
#pragma unroll
    for (int j = 0; j < 4; ++j) {
        int p = j * 16 + rr;
        ushort4 hi = make_ushort4(f2bf(t[c4 + 0][p]), f2bf(t[c4 + 1][p]),
                                  f2bf(t[c4 + 2][p]), f2bf(t[c4 + 3][p]));
        *(ushort4*)&xhi[obase + (size_t)p * 256 + c4] = hi;
    }
}

// ---------------------------------------------------------------------------
// 8-wave pipelined mainloop (R11): 128x128 tile, wave tile 64x32 (acc[4][2]).
// ---------------------------------------------------------------------------
__device__ inline void mainloop8(const unsigned short* __restrict__ Ag,
                                 const unsigned short* __restrict__ Bg,
                                 unsigned short* Al, unsigned short* Bl,
                                 int wid, int lane, int wm, int wn, f32x4 acc[4][2])
{
    const int mloc = lane & 15, ksel = lane >> 4;
    short8v rA[2], rB[2];
    load_tile2(Ag, 0, wid, lane, rA);
    load_tile2(Bg, 0, wid, lane, rB);
#pragma unroll
    for (int kc = 0; kc < 4; ++kc) {
        if (kc) __syncthreads();
        store_tile2(Al, wid, lane, rA);
        store_tile2(Bl, wid, lane, rB);
        __syncthreads();
        if (kc < 3) {
            load_tile2(Ag, (kc + 1) * 64, wid, lane, rA);
            load_tile2(Bg, (kc + 1) * 64, wid, lane, rB);
        }
#pragma unroll
        for (int kk = 0; kk < 2; ++kk) {
            const int kb = kk * 64 + ksel * 16;
            short8v a[4], bb[2];
#pragma unroll
            for (int f = 0; f < 4; ++f) a[f]  = read_frag(Al, wm * 64 + f * 16 + mloc, kb, lane);
#pragma unroll
            for (int f = 0; f < 2; ++f) bb[f] = read_frag(Bl, wn * 32 + f * 16 + mloc, kb, lane);
#pragma unroll
            for (int fm = 0; fm < 4; ++fm)
#pragma unroll
                for (int fn = 0; fn < 2; ++fn)
                    acc[fm][fn] = __builtin_amdgcn_mfma_f32_16x16x32_bf16(a[fm], bb[fn], acc[fm][fn], 0, 0, 0);
        }
    }
}

// ---------------------------------------------------------------------------
// Projection (XCD-swizzled): b = bid&7 so all blocks of batch b land on XCD b
// (L2-local xhi slice). value (mt=0,1) + aux (mt=2, hi+lo fused, softmax in
// epilogue). grid = 768, 512 threads.
// ---------------------------------------------------------------------------
__global__ __launch_bounds__(512)
void proj_kernel(const unsigned short* __restrict__ wcat_bf, const unsigned short* __restrict__ wauxlo,
                 const unsigned short* __restrict__ xhi, const float* __restrict__ bcat,
                 unsigned short* __restrict__ value_bf,
                 float* __restrict__ off_ws, float* __restrict__ attn_ws)
{
    __shared__ unsigned short lds[3 * 128 * 64];   // 48 KB
    unsigned short* Al  = lds;
    unsigned short* Bl  = lds + 128 * 64;
    unsigned short* Alo = lds + 2 * 128 * 64;

    const int bid = blockIdx.x;
    const int b    = bid & 7;            // XCD-local batch
    const int rest = bid >> 3;
    const int pt = rest & 31;
    const int mt = rest >> 5;
    const int tid = threadIdx.x, wid = tid >> 6, lane = tid & 63;
    const int wm = wid >> 2, wn = wid & 3;
    const int mloc = lane & 15, ksel = lane >> 4;

    const unsigned short* Bg = xhi + ((size_t)b * HW + pt * 128) * 256;

    f32x4 acc[4][2];
#pragma unroll
    for (int fm = 0; fm < 4; ++fm) {
        float4 bv = *(const float4*)&bcat[mt * 128 + wm * 64 + fm * 16 + ksel * 4];
#pragma unroll
        for (int fn = 0; fn < 2; ++fn) acc[fm][fn] = (f32x4){bv.x, bv.y, bv.z, bv.w};
    }

    if (mt < 2) {
        mainloop8(wcat_bf + mt * 128 * 256, Bg, Al, Bl, wid, lane, wm, wn, acc);

#pragma unroll
        for (int fm = 0; fm < 4; ++fm) {
            const int ch = mt * 128 + wm * 64 + fm * 16 + ksel * 4;
            const int head = ch >> 5, c32 = ch & 31;
#pragma unroll
            for (int fn = 0; fn < 2; ++fn) {
                const int p = pt * 128 + wn * 32 + fn * 16 + mloc;
                f32x4 v = acc[fm][fn];
                ushort4 st = make_ushort4(f2bf(v[0]), f2bf(v[1]), f2bf(v[2]), f2bf(v[3]));
                *(ushort4*)&value_bf[(((size_t)(b * 8 + head)) * HW + p) * 32 + c32] = st;
            }
        }
    } else {
        const unsigned short* Ahg = wcat_bf + 256 * 256;
        const unsigned short* Alg = wauxlo;
        short8v rA[2], rL[2], rB[2];
        load_tile2(Ahg, 0, wid, lane, rA);
        load_tile2(Alg, 0, wid, lane, rL);
        load_tile2(Bg, 0, wid, lane, rB);
#pragma unroll
        for (int kc = 0; kc < 4; ++kc) {
            if (kc) __syncthreads();
            store_tile2(Al, wid, lane, rA);
            store_tile2(Alo, wid, lane, rL);
            store_tile2(Bl, wid, lane, rB);
            __syncthreads();
            if (kc < 3) {
                load_tile2(Ahg, (kc + 1) * 64, wid, lane, rA);
                load_tile2(Alg, (kc + 1) * 64, wid, lane, rL);
                load_tile2(Bg, (kc + 1) * 64, wid, lane, rB);
            }
#pragma unroll
            for (int kk = 0; kk < 2; ++kk) {
                const int kb = kk * 64 + ksel * 16;
                short8v ah[4], al[4], bb[2];
#pragma unroll
                for (int f = 0; f < 4; ++f) {
                    ah[f] = read_frag(Al,  wm * 64 + f * 16 + mloc, kb, lane);
                    al[f] = read_frag(Alo, wm * 64 + f * 16 + mloc, kb, lane);
                }
#pragma unroll
                for (int f = 0; f < 2; ++f) bb[f] = read_frag(Bl, wn * 32 + f * 16 + mloc, kb, lane);
#pragma unroll
                for (int fm = 0; fm < 4; ++fm)
#pragma unroll
                    for (int fn = 0; fn < 2; ++fn) {
                        acc[fm][fn] = __builtin_amdgcn_mfma_f32_16x16x32_bf16(ah[fm], bb[fn], acc[fm][fn], 0, 0, 0);
                        acc[fm][fn] = __builtin_amdgcn_mfma_f32_16x16x32_bf16(al[fm], bb[fn], acc[fm][fn], 0, 0, 0);
                    }
            }
        }
#pragma unroll
        for (int fm = 0; fm < 4; ++fm) {
            const int ch0 = wm * 64 + fm * 16 + ksel * 4;
#pragma unroll
            for (int fn = 0; fn < 2; ++fn) {
                const int p = pt * 128 + wn * 32 + fn * 16 + mloc;
                f32x4 v = acc[fm][fn];
                if (ch0 < 64) {
                    *(float4*)&off_ws[((size_t)b * HW + p) * 64 + ch0] =
                        make_float4(v[0], v[1], v[2], v[3]);
                } else if (ch0 < 96) {
                    float m  = fmaxf(fmaxf(v[0], v[1]), fmaxf(v[2], v[3]));
                    float e0 = __expf(v[0] - m), e1 = __expf(v[1] - m);
                    float e2 = __expf(v[2] - m), e3 = __expf(v[3] - m);
                    float inv = 1.0f / (e0 + e1 + e2 + e3);
                    *(float4*)&attn_ws[((size_t)b * HW + p) * 32 + (ch0 - 64)] =
                        make_float4(e0 * inv, e1 * inv, e2 * inv, e3 * inv);
                }
            }
        }
    }
}

// ---------------------------------------------------------------------------
// FUSED sampling + output projection + residual. XCD-swizzled (b = bid&7).
// Phase 1: 16 threads/position, 4 heads/thread; batched corner loads.
// Phase 2: 8 waves = 4 M-tiles x 2 N-halves; K-chunks of 32 so Asm is 16 KB
//          -> total LDS 32.5 KB -> 4 blocks/CU (32 waves, full occupancy).
// grid = 8(b) * 128(pt) = 1024 blocks x 512 threads.
// ---------------------------------------------------------------------------
__global__ __launch_bounds__(512, 1)
void sampleout_kernel(const unsigned short* __restrict__ value_bf,
                      const float* __restrict__ off_ws, const float* __restrict__ attn_ws,
                      const unsigned short* __restrict__ wout_bf, const float* __restrict__ b_out,
                      const float* __restrict__ x, float* __restrict__ out)
{
    __shared__ unsigned short Wp[32 * WPITCH];   // 16.5 KB weighted panel
    __shared__ unsigned short Asm[256 * 32];     // 16 KB wout K-chunk (K=32)

    const int bid = blockIdx.x;
    const int b  = bid & 7;              // XCD-local batch
    const int pt = bid >> 3;             // 0..127
    const int tid = threadIdx.x;

    // ---- phase 1: sample (4 heads per thread, batched corner loads) ----
    {
        const int c4     = tid & 7;
        const int hh     = (tid >> 3) & 1;
        const int posIdx = tid >> 4;          // 0..31
        const int p      = pt * 32 + posIdx;
        const int h      = p >> 6;
        const int w      = p & 63;
        const float gx = w * (2.0f / 63.0f) - 1.0f;
        const float gy = h * (2.0f / 63.0f) - 1.0f;

        const float* awp  = attn_ws + ((size_t)b * HW + p) * 32;
        const float* offp = off_ws + ((size_t)b * HW + p) * 64;

#pragma unroll
        for (int hq = 0; hq < 4; ++hq) {
            const int head = hh * 4 + hq;
            float4 aw4 = *(const float4*)&awp[head * 4];
            float aw[4] = {aw4.x, aw4.y, aw4.z, aw4.w};
            float4 o01 = *(const float4*)&offp[head * 8];
            float4 o23 = *(const float4*)&offp[head * 8 + 4];
            float oxv[4] = {o01.x, o01.z, o23.x, o23.z};
            float oyv[4] = {o01.y, o01.w, o23.y, o23.w};

            const unsigned short* vb = value_bf + (size_t)(b * 8 + head) * HW * 32 + c4 * 4;

            int   adr[4][4];
            float wc[4][4];
#pragma unroll
            for (int ptq = 0; ptq < 4; ++ptq) {
                float ix = (gx + oxv[ptq] + 1.0f) * 31.5f;
                float iy = (gy + oyv[ptq] + 1.0f) * 31.5f;
                float x0f = floorf(ix), y0f = floorf(iy);
                float wx1 = ix - x0f, wx0 = 1.0f - wx1;
                float wy1 = iy - y0f, wy0 = 1.0f - wy1;
                int x0 = (int)x0f, y0 = (int)y0f;
                int x1 = x0 + 1,   y1 = y0 + 1;
                float a = aw[ptq];
                float vx0 = (x0 >= 0 && x0 <= 63) ? 1.f : 0.f;
                float vx1 = (x1 >= 0 && x1 <= 63) ? 1.f : 0.f;
                float vy0 = (y0 >= 0 && y0 <= 63) ? 1.f : 0.f;
                float vy1 = (y1 >= 0 && y1 <= 63) ? 1.f : 0.f;
                wc[ptq][0] = a * wy0 * wx0 * vy0 * vx0;
                wc[ptq][1] = a * wy0 * wx1 * vy0 * vx1;
                wc[ptq][2] = a * wy1 * wx0 * vy1 * vx0;
                wc[ptq][3] = a * wy1 * wx1 * vy1 * vx1;
                int cx0 = min(max(x0, 0), 63), cx1 = min(max(x1, 0), 63);
                int cy0 = min(max(y0, 0), 63), cy1 = min(max(y1, 0), 63);
                adr[ptq][0] = (cy0 * 64 + cx0) * 32;
                adr[ptq][1] = (cy0 * 64 + cx1) * 32;
                adr[ptq][2] = (cy1 * 64 + cx0) * 32;
                adr[ptq][3] = (cy1 * 64 + cx1) * 32;
            }
            ushort4 u[4][4];
#pragma unroll
            for (int ptq = 0; ptq < 4; ++ptq)
#pragma unroll
                for (int c = 0; c < 4; ++c)
                    u[ptq][c] = *(const ushort4*)&vb[adr[ptq][c]];
            float4 acc = make_float4(0.f, 0.f, 0.f, 0.f);
#pragma unroll
            for (int ptq = 0; ptq < 4; ++ptq)
#pragma unroll
                for (int c = 0; c < 4; ++c) {
                    float wcc = wc[ptq][c];
                    acc.x += wcc * bf2f(u[ptq][c].x);
                    acc.y += wcc * bf2f(u[ptq][c].y);
                    acc.z += wcc * bf2f(u[ptq][c].z);
                    acc.w += wcc * bf2f(u[ptq][c].w);
                }

            const int slot = head * 4 + (c4 >> 1);
            const int byte = posIdx * (WPITCH * 2) + ((slot ^ (posIdx & 7)) << 4) + (c4 & 1) * 8;
            ushort4 st = make_ushort4(f2bf(acc.x), f2bf(acc.y), f2bf(acc.z), f2bf(acc.w));
            *(ushort4*)((char*)Wp + byte) = st;
        }
    }
    __syncthreads();

    // ---- phase 2: out-proj GEMM (M=256, N=32), K-chunks of 32 (8 chunks) ----
    const int wid = tid >> 6, lane = tid & 63;
    const int wm = wid & 3, wn = wid >> 2;       // wm: 64-row M tile, wn: 16-col N half
    const int mloc = lane & 15, ksel = lane >> 4;

    f32x4 acc2[4];
#pragma unroll
    for (int fm = 0; fm < 4; ++fm) acc2[fm] = (f32x4){0.f, 0.f, 0.f, 0.f};

    // A staging map: 1024 slots (256 rows x 4 slots of 16B), thread covers 2.
    short8v rA[2];
#pragma unroll
    for (int i = 0; i < 2; ++i) {
        const int slotid = tid * 2 + i;
        rA[i] = *(const short8v*)(wout_bf + (slotid >> 2) * 256 + (slotid & 3) * 8);
    }

#pragma unroll
    for (int kc = 0; kc < 8; ++kc) {
        if (kc) __syncthreads();
#pragma unroll
        for (int i = 0; i < 2; ++i) {
            const int slotid = tid * 2 + i;
            const int row = slotid >> 2, s = slotid & 3;
            *(short8v*)((char*)Asm + row * 64 + ((s ^ (row & 3)) << 4)) = rA[i];
        }
        __syncthreads();
        if (kc < 7) {
#pragma unroll
            for (int i = 0; i < 2; ++i) {
                const int slotid = tid * 2 + i;
                rA[i] = *(const short8v*)(wout_bf + (slotid >> 2) * 256 + (kc + 1) * 32 + (slotid & 3) * 8);
            }
        }
        short8v a[4], bb;
#pragma unroll
        for (int f = 0; f < 4; ++f) {
            const int row = wm * 64 + f * 16 + mloc;
            a[f] = *(const short8v*)((char*)Asm + row * 64 + ((ksel ^ (row & 3)) << 4));
        }
        {
            const int row = wn * 16 + mloc;
            const int slot = kc * 4 + ksel;
            bb = *(const short8v*)((char*)Wp + row * (WPITCH * 2) + ((slot ^ (row & 7)) << 4));
        }
#pragma unroll
        for (int fm = 0; fm < 4; ++fm)
            acc2[fm] = __builtin_amdgcn_mfma_f32_16x16x32_bf16(a[fm], bb, acc2[fm], 0, 0, 0);
    }

#pragma unroll
    for (int fm = 0; fm < 4; ++fm) {
        const int o = wm * 64 + fm * 16 + ksel * 4;
        float4 bo = *(const float4*)&b_out[o];
        const int p = pt * 32 + wn * 16 + mloc;
        const size_t idx = ((size_t)(b * 256 + o)) * HW + p;
        f32x4 v = acc2[fm];
        out[idx + 0 * HW] = v[0] + bo.x + x[idx + 0 * HW];
        out[idx + 1 * HW] = v[1] + bo.y + x[idx + 1 * HW];
        out[idx + 2 * HW] = v[2] + bo.z + x[idx + 2 * HW];
        out[idx + 3 * HW] = v[3] + bo.w + x[idx + 3 * HW];
    }
}

// ---------------------------------------------------------------------------
extern "C" void kernel_launch(void* const* d_in, const int* in_sizes, int n_in,
                              void* d_out, int out_size, void* d_ws, size_t ws_size,
                              hipStream_t stream)
{
    const float* x      = (const float*)d_in[0];
    const float* w_off  = (const float*)d_in[1];
    const float* b_off  = (const float*)d_in[2];
    const float* w_attn = (const float*)d_in[3];
    const float* b_attn = (const float*)d_in[4];
    const float* w_val  = (const float*)d_in[5];
    const float* b_val  = (const float*)d_in[6];
    const float* w_out  = (const float*)d_in[7];
    const float* b_out  = (const float*)d_in[8];
    float* out = (float*)d_out;

    char* ws = (char*)d_ws;
    unsigned short* wcat_bf = (unsigned short*)(ws + 0);          //  196608 B
    unsigned short* wauxlo  = (unsigned short*)(ws + 196608);     //   65536 B
    unsigned short* wout_bf = (unsigned short*)(ws + 262144);     //  131072 B
    float*          bcat    = (float*)(ws + 393216);              //    2048 B
    unsigned short* xhi     = (unsigned short*)(ws + 395264);     // 16777216 B
    unsigned short* val_bf  = (unsigned short*)(ws + 17172480);   // 16777216 B
    float*          off_ws  = (float*)(ws + 33949696);            //  8388608 B  [b][p][64]
    float*          attn_ws = (float*)(ws + 42338304);            //  4194304 B  [b][p][32] (softmax weights)

    prep_kernel<<<384, 256, 0, stream>>>(w_off, b_off, w_attn, b_attn, w_val, b_val,
                                         w_out, wcat_bf, wauxlo, wout_bf, bcat);
    transpose_kernel<<<2048, 256, 0, stream>>>(x, xhi);
    proj_kernel<<<768, 512, 0, stream>>>(wcat_bf, wauxlo, xhi, bcat, val_bf, off_ws, attn_ws);
    sampleout_kernel<<<1024, 512, 0, stream>>>(val_bf, off_ws, attn_ws, wout_bf, b_out, x, out);
}

// Round 23
// 68.532 us; speedup vs baseline: 1.0416x; 1.0416x over previous
//
#include <hip/hip_runtime.h>
#include <cstddef>

#define HW 4096
#define WPITCH 264   // shorts per Wp row (528 B)

typedef __attribute__((ext_vector_type(8))) short short8v;   // 8 bf16
typedef __attribute__((ext_vector_type(4))) float f32x4;     // 4 fp32

__device__ inline unsigned short f2bf(float f) {
    unsigned int u = __float_as_uint(f);
    u += 0x7FFFu + ((u >> 16) & 1u);
    return (unsigned short)(u >> 16);
}
__device__ inline float bf2f(unsigned short s) {
    return __uint_as_float(((unsigned int)s) << 16);
}

// ---------------------------------------------------------------------------
// Reg-staged tile movement for a [128 rows][64 bf16] tile (16 KB), 512-thread
// blocks: per thread 2 x 16B. Layout: slot s of row r at r*128 + ((s^(r&7))<<4).
// ---------------------------------------------------------------------------
__device__ inline void load_tile2(const unsigned short* __restrict__ g, int kc,
                                  int wid, int lane, short8v r[2])
{
    const int s  = lane & 7;
    const int r8 = lane >> 3;
    const unsigned short* src = g + kc + s * 8;
#pragma unroll
    for (int i = 0; i < 2; ++i) {
        const int row = wid * 16 + i * 8 + r8;
        r[i] = *(const short8v*)(src + row * 256);
    }
}

__device__ inline void store_tile2(unsigned short* lds, int wid, int lane, const short8v r[2])
{
    const int s  = lane & 7;
    const int r8 = lane >> 3;
#pragma unroll
    for (int i = 0; i < 2; ++i) {
        const int row = wid * 16 + i * 8 + r8;
        *(short8v*)((char*)lds + row * 128 + ((s ^ (row & 7)) << 4)) = r[i];
    }
}

__device__ inline short8v read_frag(const unsigned short* lds, int row, int kbyte, int lane)
{
    const char* p = (const char*)lds + row * 128 + (kbyte ^ ((lane & 7) * 16));
    return *(const short8v*)p;
}

// ---------------------------------------------------------------------------
// Prep: bf16 weights (row-major), lo-plane for aux weight rows, fp32 biases.
// ---------------------------------------------------------------------------
__global__ __launch_bounds__(256)
void prep_kernel(const float* __restrict__ w_off, const float* __restrict__ b_off,
                 const float* __restrict__ w_attn, const float* __restrict__ b_attn,
                 const float* __restrict__ w_val, const float* __restrict__ b_val,
                 const float* __restrict__ w_out,
                 unsigned short* __restrict__ wcat_bf, unsigned short* __restrict__ wauxlo,
                 unsigned short* __restrict__ wout_bf, float* __restrict__ bcat)
{
    int i = blockIdx.x * 256 + threadIdx.x;
    if (i < 384 * 256) {
        int n = i >> 8, k = i & 255;
        float v;
        if (n < 256)      v = w_val[n * 256 + k];
        else if (n < 320) v = w_off[(n - 256) * 256 + k];
        else if (n < 352) v = w_attn[(n - 320) * 256 + k];
        else              v = 0.0f;
        unsigned short hi = f2bf(v);
        wcat_bf[i] = hi;
        if (n >= 256) wauxlo[(n - 256) * 256 + k] = f2bf(v - bf2f(hi));
    }
    if (i < 128 * 256) {
        int n = i >> 8;
        if (n >= 96) wauxlo[i] = 0;
    }
    if (i < 256 * 256) wout_bf[i] = f2bf(w_out[i]);
    if (i < 512) {
        float v = 0.0f;
        if (i < 256)      v = b_val[i];
        else if (i < 320) v = b_off[i - 256];
        else if (i < 352) v = b_attn[i - 320];
        bcat[i] = v;
    }
}

// ---------------------------------------------------------------------------
// Transpose x: fp32 [b][c][4096] -> bf16 [b][p][256]
// ---------------------------------------------------------------------------
__global__ __launch_bounds__(256)
void transpose_kernel(const float* __restrict__ x, unsigned short* __restrict__ xhi)
{
    __shared__ float t[64][65];
    const int bid = blockIdx.x;
    const int pt = bid & 63, ct = (bid >> 6) & 3, b = bid >> 8;
    const int tid = threadIdx.x;
    const int rr = tid >> 4, c4 = (tid & 15) * 4;

    const float* src = x + ((size_t)(b * 256 + ct * 64)) * HW + pt * 64;
#pragma unroll
    for (int j = 0; j < 4; ++j) {
        float4 v = *(const float4*)&src[(size_t)(j * 16 + rr) * HW + c4];
        t[j * 16 + rr][c4 + 0] = v.x; t[j * 16 + rr][c4 + 1] = v.y;
        t[j * 16 + rr][c4 + 2] = v.z; t[j * 16 + rr][c4 + 3] = v.w;
    }
    __syncthreads();

    const size_t obase = ((size_t)b * HW + pt * 64) * 256 + ct * 64;
#pragma unroll
    for (int j = 0; j < 4; ++j) {
        int p = j * 16 + rr;
        ushort4 hi = make_ushort4(f2bf(t[c4 + 0][p]), f2bf(t[c4 + 1][p]),
                                  f2bf(t[c4 + 2][p]), f2bf(t[c4 + 3][p]));
        *(ushort4*)&xhi[obase + (size_t)p * 256 + c4] = hi;
    }
}

// ---------------------------------------------------------------------------
// 8-wave pipelined mainloop (R11): 128x128 tile, wave tile 64x32 (acc[4][2]).
// ---------------------------------------------------------------------------
__device__ inline void mainloop8(const unsigned short* __restrict__ Ag,
                                 const unsigned short* __restrict__ Bg,
                                 unsigned short* Al, unsigned short* Bl,
                                 int wid, int lane, int wm, int wn, f32x4 acc[4][2])
{
    const int mloc = lane & 15, ksel = lane >> 4;
    short8v rA[2], rB[2];
    load_tile2(Ag, 0, wid, lane, rA);
    load_tile2(Bg, 0, wid, lane, rB);
#pragma unroll
    for (int kc = 0; kc < 4; ++kc) {
        if (kc) __syncthreads();
        store_tile2(Al, wid, lane, rA);
        store_tile2(Bl, wid, lane, rB);
        __syncthreads();
        if (kc < 3) {
            load_tile2(Ag, (kc + 1) * 64, wid, lane, rA);
            load_tile2(Bg, (kc + 1) * 64, wid, lane, rB);
        }
#pragma unroll
        for (int kk = 0; kk < 2; ++kk) {
            const int kb = kk * 64 + ksel * 16;
            short8v a[4], bb[2];
#pragma unroll
            for (int f = 0; f < 4; ++f) a[f]  = read_frag(Al, wm * 64 + f * 16 + mloc, kb, lane);
#pragma unroll
            for (int f = 0; f < 2; ++f) bb[f] = read_frag(Bl, wn * 32 + f * 16 + mloc, kb, lane);
#pragma unroll
            for (int fm = 0; fm < 4; ++fm)
#pragma unroll
                for (int fn = 0; fn < 2; ++fn)
                    acc[fm][fn] = __builtin_amdgcn_mfma_f32_16x16x32_bf16(a[fm], bb[fn], acc[fm][fn], 0, 0, 0);
        }
    }
}

// ---------------------------------------------------------------------------
// Projection (XCD-swizzled): b = bid&7 so all blocks of batch b land on XCD b
// (L2-local xhi slice). value (mt=0,1) + aux (mt=2, hi+lo fused, softmax in
// epilogue). grid = 768, 512 threads.
// ---------------------------------------------------------------------------
__global__ __launch_bounds__(512)
void proj_kernel(const unsigned short* __restrict__ wcat_bf, const unsigned short* __restrict__ wauxlo,
                 const unsigned short* __restrict__ xhi, const float* __restrict__ bcat,
                 unsigned short* __restrict__ value_bf,
                 float* __restrict__ off_ws, float* __restrict__ attn_ws)
{
    __shared__ unsigned short lds[3 * 128 * 64];   // 48 KB
    unsigned short* Al  = lds;
    unsigned short* Bl  = lds + 128 * 64;
    unsigned short* Alo = lds + 2 * 128 * 64;

    const int bid = blockIdx.x;
    const int b    = bid & 7;            // XCD-local batch
    const int rest = bid >> 3;
    const int pt = rest & 31;
    const int mt = rest >> 5;
    const int tid = threadIdx.x, wid = tid >> 6, lane = tid & 63;
    const int wm = wid >> 2, wn = wid & 3;
    const int mloc = lane & 15, ksel = lane >> 4;

    const unsigned short* Bg = xhi + ((size_t)b * HW + pt * 128) * 256;

    f32x4 acc[4][2];
#pragma unroll
    for (int fm = 0; fm < 4; ++fm) {
        float4 bv = *(const float4*)&bcat[mt * 128 + wm * 64 + fm * 16 + ksel * 4];
#pragma unroll
        for (int fn = 0; fn < 2; ++fn) acc[fm][fn] = (f32x4){bv.x, bv.y, bv.z, bv.w};
    }

    if (mt < 2) {
        mainloop8(wcat_bf + mt * 128 * 256, Bg, Al, Bl, wid, lane, wm, wn, acc);

#pragma unroll
        for (int fm = 0; fm < 4; ++fm) {
            const int ch = mt * 128 + wm * 64 + fm * 16 + ksel * 4;
            const int head = ch >> 5, c32 = ch & 31;
#pragma unroll
            for (int fn = 0; fn < 2; ++fn) {
                const int p = pt * 128 + wn * 32 + fn * 16 + mloc;
                f32x4 v = acc[fm][fn];
                ushort4 st = make_ushort4(f2bf(v[0]), f2bf(v[1]), f2bf(v[2]), f2bf(v[3]));
                *(ushort4*)&value_bf[(((size_t)(b * 8 + head)) * HW + p) * 32 + c32] = st;
            }
        }
    } else {
        const unsigned short* Ahg = wcat_bf + 256 * 256;
        const unsigned short* Alg = wauxlo;
        short8v rA[2], rL[2], rB[2];
        load_tile2(Ahg, 0, wid, lane, rA);
        load_tile2(Alg, 0, wid, lane, rL);
        load_tile2(Bg, 0, wid, lane, rB);
#pragma unroll
        for (int kc = 0; kc < 4; ++kc) {
            if (kc) __syncthreads();
            store_tile2(Al, wid, lane, rA);
            store_tile2(Alo, wid, lane, rL);
            store_tile2(Bl, wid, lane, rB);
            __syncthreads();
            if (kc < 3) {
                load_tile2(Ahg, (kc + 1) * 64, wid, lane, rA);
                load_tile2(Alg, (kc + 1) * 64, wid, lane, rL);
                load_tile2(Bg, (kc + 1) * 64, wid, lane, rB);
            }
#pragma unroll
            for (int kk = 0; kk < 2; ++kk) {
                const int kb = kk * 64 + ksel * 16;
                short8v ah[4], al[4], bb[2];
#pragma unroll
                for (int f = 0; f < 4; ++f) {
                    ah[f] = read_frag(Al,  wm * 64 + f * 16 + mloc, kb, lane);
                    al[f] = read_frag(Alo, wm * 64 + f * 16 + mloc, kb, lane);
                }
#pragma unroll
                for (int f = 0; f < 2; ++f) bb[f] = read_frag(Bl, wn * 32 + f * 16 + mloc, kb, lane);
#pragma unroll
                for (int fm = 0; fm < 4; ++fm)
#pragma unroll
                    for (int fn = 0; fn < 2; ++fn) {
                        acc[fm][fn] = __builtin_amdgcn_mfma_f32_16x16x32_bf16(ah[fm], bb[fn], acc[fm][fn], 0, 0, 0);
                        acc[fm][fn] = __builtin_amdgcn_mfma_f32_16x16x32_bf16(al[fm], bb[fn], acc[fm][fn], 0, 0, 0);
                    }
            }
        }
#pragma unroll
        for (int fm = 0; fm < 4; ++fm) {
            const int ch0 = wm * 64 + fm * 16 + ksel * 4;
#pragma unroll
            for (int fn = 0; fn < 2; ++fn) {
                const int p = pt * 128 + wn * 32 + fn * 16 + mloc;
                f32x4 v = acc[fm][fn];
                if (ch0 < 64) {
                    *(float4*)&off_ws[((size_t)b * HW + p) * 64 + ch0] =
                        make_float4(v[0], v[1], v[2], v[3]);
                } else if (ch0 < 96) {
                    float m  = fmaxf(fmaxf(v[0], v[1]), fmaxf(v[2], v[3]));
                    float e0 = __expf(v[0] - m), e1 = __expf(v[1] - m);
                    float e2 = __expf(v[2] - m), e3 = __expf(v[3] - m);
                    float inv = 1.0f / (e0 + e1 + e2 + e3);
                    *(float4*)&attn_ws[((size_t)b * HW + p) * 32 + (ch0 - 64)] =
                        make_float4(e0 * inv, e1 * inv, e2 * inv, e3 * inv);
                }
            }
        }
    }
}

// ---------------------------------------------------------------------------
// FUSED sampling + output projection + residual. XCD-swizzled (b = bid&7).
// Phase 1: 16 threads/position, 4 heads/thread; batched corner loads.
// Phase 2: 8 waves = 4 M-tiles (64 rows, a[4]/acc2[4]) x 2 N-halves of 16.
// grid = 8(b) * 128(pt) = 1024 blocks x 512 threads.
// ---------------------------------------------------------------------------
__global__ __launch_bounds__(512, 1)
void sampleout_kernel(const unsigned short* __restrict__ value_bf,
                      const float* __restrict__ off_ws, const float* __restrict__ attn_ws,
                      const unsigned short* __restrict__ wout_bf, const float* __restrict__ b_out,
                      const float* __restrict__ x, float* __restrict__ out)
{
    __shared__ unsigned short Wp[32 * WPITCH];   // 16.5 KB weighted panel
    __shared__ unsigned short Asm[256 * 64];     // 32 KB wout K-chunk

    const int bid = blockIdx.x;
    const int b  = bid & 7;              // XCD-local batch
    const int pt = bid >> 3;             // 0..127
    const int tid = threadIdx.x;

    // ---- phase 1: sample (4 heads per thread, batched corner loads) ----
    {
        const int c4     = tid & 7;
        const int hh     = (tid >> 3) & 1;
        const int posIdx = tid >> 4;          // 0..31
        const int p      = pt * 32 + posIdx;
        const int h      = p >> 6;
        const int w      = p & 63;
        const float gx = w * (2.0f / 63.0f) - 1.0f;
        const float gy = h * (2.0f / 63.0f) - 1.0f;

        const float* awp  = attn_ws + ((size_t)b * HW + p) * 32;
        const float* offp = off_ws + ((size_t)b * HW + p) * 64;

#pragma unroll
        for (int hq = 0; hq < 4; ++hq) {
            const int head = hh * 4 + hq;
            float4 aw4 = *(const float4*)&awp[head * 4];
            float aw[4] = {aw4.x, aw4.y, aw4.z, aw4.w};
            float4 o01 = *(const float4*)&offp[head * 8];
            float4 o23 = *(const float4*)&offp[head * 8 + 4];
            float oxv[4] = {o01.x, o01.z, o23.x, o23.z};
            float oyv[4] = {o01.y, o01.w, o23.y, o23.w};

            const unsigned short* vb = value_bf + (size_t)(b * 8 + head) * HW * 32 + c4 * 4;

            int   adr[4][4];
            float wc[4][4];
#pragma unroll
            for (int ptq = 0; ptq < 4; ++ptq) {
                float ix = (gx + oxv[ptq] + 1.0f) * 31.5f;
                float iy = (gy + oyv[ptq] + 1.0f) * 31.5f;
                float x0f = floorf(ix), y0f = floorf(iy);
                float wx1 = ix - x0f, wx0 = 1.0f - wx1;
                float wy1 = iy - y0f, wy0 = 1.0f - wy1;
                int x0 = (int)x0f, y0 = (int)y0f;
                int x1 = x0 + 1,   y1 = y0 + 1;
                float a = aw[ptq];
                float vx0 = (x0 >= 0 && x0 <= 63) ? 1.f : 0.f;
                float vx1 = (x1 >= 0 && x1 <= 63) ? 1.f : 0.f;
                float vy0 = (y0 >= 0 && y0 <= 63) ? 1.f : 0.f;
                float vy1 = (y1 >= 0 && y1 <= 63) ? 1.f : 0.f;
                wc[ptq][0] = a * wy0 * wx0 * vy0 * vx0;
                wc[ptq][1] = a * wy0 * wx1 * vy0 * vx1;
                wc[ptq][2] = a * wy1 * wx0 * vy1 * vx0;
                wc[ptq][3] = a * wy1 * wx1 * vy1 * vx1;
                int cx0 = min(max(x0, 0), 63), cx1 = min(max(x1, 0), 63);
                int cy0 = min(max(y0, 0), 63), cy1 = min(max(y1, 0), 63);
                adr[ptq][0] = (cy0 * 64 + cx0) * 32;
                adr[ptq][1] = (cy0 * 64 + cx1) * 32;
                adr[ptq][2] = (cy1 * 64 + cx0) * 32;
                adr[ptq][3] = (cy1 * 64 + cx1) * 32;
            }
            ushort4 u[4][4];
#pragma unroll
            for (int ptq = 0; ptq < 4; ++ptq)
#pragma unroll
                for (int c = 0; c < 4; ++c)
                    u[ptq][c] = *(const ushort4*)&vb[adr[ptq][c]];
            float4 acc = make_float4(0.f, 0.f, 0.f, 0.f);
#pragma unroll
            for (int ptq = 0; ptq < 4; ++ptq)
#pragma unroll
                for (int c = 0; c < 4; ++c) {
                    float wcc = wc[ptq][c];
                    acc.x += wcc * bf2f(u[ptq][c].x);
                    acc.y += wcc * bf2f(u[ptq][c].y);
                    acc.z += wcc * bf2f(u[ptq][c].z);
                    acc.w += wcc * bf2f(u[ptq][c].w);
                }

            const int slot = head * 4 + (c4 >> 1);
            const int byte = posIdx * (WPITCH * 2) + ((slot ^ (posIdx & 7)) << 4) + (c4 & 1) * 8;
            ushort4 st = make_ushort4(f2bf(acc.x), f2bf(acc.y), f2bf(acc.z), f2bf(acc.w));
            *(ushort4*)((char*)Wp + byte) = st;
        }
    }
    __syncthreads();

    // ---- phase 2: out-proj GEMM (M=256, N=32), 4 M-tiles x 2 N-halves ----
    const int wid = tid >> 6, lane = tid & 63;
    const int wm = wid & 3, wn = wid >> 2;       // wm: 64-row M tile, wn: 16-col N half
    const int mloc = lane & 15, ksel = lane >> 4;
    const int s = lane & 7, r8 = lane >> 3;

    f32x4 acc2[4];
#pragma unroll
    for (int fm = 0; fm < 4; ++fm) acc2[fm] = (f32x4){0.f, 0.f, 0.f, 0.f};

    short8v rA[4];
#pragma unroll
    for (int i = 0; i < 4; ++i)
        rA[i] = *(const short8v*)(wout_bf + (wid * 32 + i * 8 + r8) * 256 + s * 8);

#pragma unroll
    for (int kc = 0; kc < 4; ++kc) {
        if (kc) __syncthreads();
#pragma unroll
        for (int i = 0; i < 4; ++i) {
            const int row = wid * 32 + i * 8 + r8;
            *(short8v*)((char*)Asm + row * 128 + ((s ^ (row & 7)) << 4)) = rA[i];
        }
        __syncthreads();
        if (kc < 3) {
#pragma unroll
            for (int i = 0; i < 4; ++i)
                rA[i] = *(const short8v*)(wout_bf + (wid * 32 + i * 8 + r8) * 256 + (kc + 1) * 64 + s * 8);
        }
#pragma unroll
        for (int kk = 0; kk < 2; ++kk) {
            short8v a[4], bb;
#pragma unroll
            for (int f = 0; f < 4; ++f) {
                const int row = wm * 64 + f * 16 + mloc;
                a[f] = *(const short8v*)((char*)Asm + row * 128 + (((kk * 4 + ksel) ^ (row & 7)) << 4));
            }
            {
                const int row = wn * 16 + mloc;
                const int slot = kc * 8 + kk * 4 + ksel;
                bb = *(const short8v*)((char*)Wp + row * (WPITCH * 2) + ((slot ^ (row & 7)) << 4));
            }
#pragma unroll
            for (int fm = 0; fm < 4; ++fm)
                acc2[fm] = __builtin_amdgcn_mfma_f32_16x16x32_bf16(a[fm], bb, acc2[fm], 0, 0, 0);
        }
    }

#pragma unroll
    for (int fm = 0; fm < 4; ++fm) {
        const int o = wm * 64 + fm * 16 + ksel * 4;
        float4 bo = *(const float4*)&b_out[o];
        const int p = pt * 32 + wn * 16 + mloc;
        const size_t idx = ((size_t)(b * 256 + o)) * HW + p;
        f32x4 v = acc2[fm];
        out[idx + 0 * HW] = v[0] + bo.x + x[idx + 0 * HW];
        out[idx + 1 * HW] = v[1] + bo.y + x[idx + 1 * HW];
        out[idx + 2 * HW] = v[2] + bo.z + x[idx + 2 * HW];
        out[idx + 3 * HW] = v[3] + bo.w + x[idx + 3 * HW];
    }
}

// ---------------------------------------------------------------------------
extern "C" void kernel_launch(void* const* d_in, const int* in_sizes, int n_in,
                              void* d_out, int out_size, void* d_ws, size_t ws_size,
                              hipStream_t stream)
{
    const float* x      = (const float*)d_in[0];
    const float* w_off  = (const float*)d_in[1];
    const float* b_off  = (const float*)d_in[2];
    const float* w_attn = (const float*)d_in[3];
    const float* b_attn = (const float*)d_in[4];
    const float* w_val  = (const float*)d_in[5];
    const float* b_val  = (const float*)d_in[6];
    const float* w_out  = (const float*)d_in[7];
    const float* b_out  = (const float*)d_in[8];
    float* out = (float*)d_out;

    char* ws = (char*)d_ws;
    unsigned short* wcat_bf = (unsigned short*)(ws + 0);          //  196608 B
    unsigned short* wauxlo  = (unsigned short*)(ws + 196608);     //   65536 B
    unsigned short* wout_bf = (unsigned short*)(ws + 262144);     //  131072 B
    float*          bcat    = (float*)(ws + 393216);              //    2048 B
    unsigned short* xhi     = (unsigned short*)(ws + 395264);     // 16777216 B
    unsigned short* val_bf  = (unsigned short*)(ws + 17172480);   // 16777216 B
    float*          off_ws  = (float*)(ws + 33949696);            //  8388608 B  [b][p][64]
    float*          attn_ws = (float*)(ws + 42338304);            //  4194304 B  [b][p][32] (softmax weights)

    prep_kernel<<<384, 256, 0, stream>>>(w_off, b_off, w_attn, b_attn, w_val, b_val,
                                         w_out, wcat_bf, wauxlo, wout_bf, bcat);
    transpose_kernel<<<2048, 256, 0, stream>>>(x, xhi);
    proj_kernel<<<768, 512, 0, stream>>>(wcat_bf, wauxlo, xhi, bcat, val_bf, off_ws, attn_ws);
    sampleout_kernel<<<1024, 512, 0, stream>>>(val_bf, off_ws, attn_ws, wout_bf, b_out, x, out);
}